// Round 3
// baseline (622.984 us; speedup 1.0000x reference)
//
#include <hip/hip_runtime.h>
#include <hip/hip_bf16.h>

// MultiHeadSelfAttentionEinSum2D: B=8,P=4,N=1024,D=384,H=8,PD=48
// Pipeline: prep (transpose weights to bf16, k-contiguous) -> QKV GEMM (MFMA)
//           -> flash attention (MFMA) -> output projection GEMM (MFMA)

#define BP 32
#define NN 1024
#define DD 384
#define HH 8
#define PDIM 48
#define E3 144
#define OO 1152
#define EP 64

typedef unsigned short u16;
typedef __attribute__((ext_vector_type(8))) short short8;
typedef __attribute__((ext_vector_type(4))) float f32x4;

__device__ __forceinline__ u16 f2bf(float f) {
    union { float f; unsigned int u; } v;
    v.f = f;
    unsigned int u = v.u;
    unsigned int r = u + 0x7FFFu + ((u >> 16) & 1u);  // RNE
    return (u16)(r >> 16);
}

// ---------------- prep: transpose weights into bf16, k-contiguous ----------------
// Wt[o][d]  = w_qkv[d][o]          (o = h*144 + e3, 1152 x 384)
// Wot[d][he] = w_o[e][h][d]        (he = h*48 + e,  384 x 384)
__global__ void prep_kernel(const float* __restrict__ w_qkv,
                            const float* __restrict__ w_o,
                            u16* __restrict__ Wt, u16* __restrict__ Wot) {
    int total1 = OO * DD;   // 442368
    int total2 = DD * DD;   // 147456
    for (int i = blockIdx.x * blockDim.x + threadIdx.x; i < total1 + total2;
         i += gridDim.x * blockDim.x) {
        if (i < total1) {
            int o = i / DD, d = i - o * DD;
            Wt[(size_t)o * DD + d] = f2bf(w_qkv[(size_t)d * OO + o]);
        } else {
            int j = i - total1;
            int d = j / DD, he = j - d * DD;
            int h = he / PDIM, e = he - h * PDIM;
            Wot[(size_t)d * DD + he] = f2bf(w_o[((size_t)e * HH + h) * DD + d]);
        }
    }
}

// ---------------- QKV projection GEMM ----------------
// grid (16 row-tiles, 32 bp, 4 head-pairs), block 256 (4 waves)
// wave computes 16 rows x 288 cols (2 heads). A = x (fp32->bf16 inline), B = Wt.
__global__ __launch_bounds__(256) void qkv_kernel(
    const float* __restrict__ x, const float* __restrict__ b_qkv,
    const u16* __restrict__ Wt,
    u16* __restrict__ q_ws, u16* __restrict__ k_ws, u16* __restrict__ vt_ws) {
    int rt = blockIdx.x;        // 0..15
    int bp = blockIdx.y;        // 0..31
    int hp = blockIdx.z;        // 0..3  (heads 2hp, 2hp+1)
    int tid = threadIdx.x;
    int w = tid >> 6, l = tid & 63;
    int lr = l & 15, lg = l >> 4;
    int n = rt * 64 + w * 16 + lr;  // A-frag row
    const float* xrow = x + ((size_t)bp * NN + n) * DD;
    int obase = hp * 288;

    f32x4 acc[18];
#pragma unroll
    for (int i = 0; i < 18; ++i) acc[i] = (f32x4)(0.f);

#pragma unroll 1
    for (int ks = 0; ks < 12; ++ks) {
        int k0 = ks * 32 + lg * 8;
        float4 a0 = *reinterpret_cast<const float4*>(xrow + k0);
        float4 a1 = *reinterpret_cast<const float4*>(xrow + k0 + 4);
        short8 af;
        af[0] = (short)f2bf(a0.x); af[1] = (short)f2bf(a0.y);
        af[2] = (short)f2bf(a0.z); af[3] = (short)f2bf(a0.w);
        af[4] = (short)f2bf(a1.x); af[5] = (short)f2bf(a1.y);
        af[6] = (short)f2bf(a1.z); af[7] = (short)f2bf(a1.w);
#pragma unroll
        for (int ct = 0; ct < 18; ++ct) {
            int o = obase + ct * 16 + lr;
            short8 bf = *reinterpret_cast<const short8*>(Wt + (size_t)o * DD + k0);
            acc[ct] = __builtin_amdgcn_mfma_f32_16x16x32_bf16(af, bf, acc[ct], 0, 0, 0);
        }
    }

    // epilogue: scatter into q/k (padded [n][64]) and v^T ([e][n]); pad cols zeroed here
#pragma unroll
    for (int ct = 0; ct < 18; ++ct) {
        int o = obase + ct * 16 + lr;
        int h = o / E3, e3 = o - h * E3;
        size_t bph = (size_t)bp * HH + h;
        float bias = b_qkv[o];
#pragma unroll
        for (int r = 0; r < 4; ++r) {
            int nn = rt * 64 + w * 16 + lg * 4 + r;
            u16 bv = f2bf(acc[ct][r] + bias);
            if (e3 < 48) {
                size_t base = (bph * NN + nn) * EP;
                q_ws[base + e3] = bv;
                if (e3 < 16) q_ws[base + 48 + e3] = 0;
            } else if (e3 < 96) {
                int c = e3 - 48;
                size_t base = (bph * NN + nn) * EP;
                k_ws[base + c] = bv;
                if (c < 16) k_ws[base + 48 + c] = 0;
            } else {
                int e = e3 - 96;
                vt_ws[(bph * PDIM + e) * NN + nn] = bv;
            }
        }
    }
}

// ---------------- flash attention ----------------
// grid (16 row-tiles, 256 bph), block 256 (4 waves, 16 Q-rows each)
__global__ __launch_bounds__(256) void attn_kernel(
    const u16* __restrict__ q_ws, const u16* __restrict__ k_ws,
    const u16* __restrict__ vt_ws, u16* __restrict__ wv_ws) {
    int rt = blockIdx.x;    // 0..15
    int bph = blockIdx.y;   // 0..255
    int bp = bph >> 3, h = bph & 7;
    int tid = threadIdx.x;
    int w = tid >> 6, l = tid & 63;
    int lr = l & 15, lg = l >> 4;

    __shared__ alignas(16) u16 Klds[64][72];       // j x e(pad64), stride-72 kills bank conflicts
    __shared__ alignas(16) u16 Vlds[48][72];       // e x j
    __shared__ alignas(16) u16 Plds[4][16][72];    // per-wave P tile (C-layout -> A-layout)

    // Q fragments for this wave's 16 rows (held in registers across the j-loop)
    int qn = rt * 64 + w * 16 + lr;
    const u16* qrow = q_ws + ((size_t)bph * NN + qn) * EP;
    short8 aq0 = *reinterpret_cast<const short8*>(qrow + lg * 8);
    short8 aq1 = *reinterpret_cast<const short8*>(qrow + 32 + lg * 8);

    f32x4 accO[3];
#pragma unroll
    for (int i = 0; i < 3; ++i) accO[i] = (f32x4)(0.f);
    float mrun[4], lrun[4];
#pragma unroll
    for (int r = 0; r < 4; ++r) { mrun[r] = -1e30f; lrun[r] = 0.f; }
    const float inv_scale = 0.14433756729740643f;  // 1/sqrt(48)

#pragma unroll 1
    for (int jc = 0; jc < 16; ++jc) {
        // cooperative stage of K-chunk [64][64] and V^T-chunk [48][64]
        {
            int j = tid >> 2, seg = (tid & 3) * 16;
            const u16* src = k_ws + ((size_t)bph * NN + jc * 64 + j) * EP + seg;
            *reinterpret_cast<short8*>(&Klds[j][seg]) = *reinterpret_cast<const short8*>(src);
            *reinterpret_cast<short8*>(&Klds[j][seg + 8]) = *reinterpret_cast<const short8*>(src + 8);
            if (tid < 192) {
                int e = tid >> 2;
                const u16* vsrc = vt_ws + ((size_t)bph * PDIM + e) * NN + jc * 64 + seg;
                *reinterpret_cast<short8*>(&Vlds[e][seg]) = *reinterpret_cast<const short8*>(vsrc);
                *reinterpret_cast<short8*>(&Vlds[e][seg + 8]) = *reinterpret_cast<const short8*>(vsrc + 8);
            }
        }
        __syncthreads();

        // S = Q K^T for this wave's 16 rows x 64 cols
        f32x4 s[4];
#pragma unroll
        for (int ct = 0; ct < 4; ++ct) {
            s[ct] = (f32x4)(0.f);
            short8 bk0 = *reinterpret_cast<const short8*>(&Klds[ct * 16 + lr][lg * 8]);
            short8 bk1 = *reinterpret_cast<const short8*>(&Klds[ct * 16 + lr][32 + lg * 8]);
            s[ct] = __builtin_amdgcn_mfma_f32_16x16x32_bf16(aq0, bk0, s[ct], 0, 0, 0);
            s[ct] = __builtin_amdgcn_mfma_f32_16x16x32_bf16(aq1, bk1, s[ct], 0, 0, 0);
        }
#pragma unroll
        for (int ct = 0; ct < 4; ++ct) s[ct] *= inv_scale;

        // online softmax (row r lives in reg r of the 16 lanes sharing lane>>4)
        float mnew[4], alpha[4];
#pragma unroll
        for (int r = 0; r < 4; ++r) {
            float m = fmaxf(fmaxf(s[0][r], s[1][r]), fmaxf(s[2][r], s[3][r]));
#pragma unroll
            for (int off = 1; off < 16; off <<= 1) m = fmaxf(m, __shfl_xor(m, off));
            mnew[r] = fmaxf(mrun[r], m);
            alpha[r] = __expf(mrun[r] - mnew[r]);
            mrun[r] = mnew[r];
        }
        float p[4][4];
#pragma unroll
        for (int ct = 0; ct < 4; ++ct)
#pragma unroll
            for (int r = 0; r < 4; ++r) p[ct][r] = __expf(s[ct][r] - mnew[r]);
#pragma unroll
        for (int r = 0; r < 4; ++r) {
            float rs = p[0][r] + p[1][r] + p[2][r] + p[3][r];
#pragma unroll
            for (int off = 1; off < 16; off <<= 1) rs += __shfl_xor(rs, off);
            lrun[r] = lrun[r] * alpha[r] + rs;
        }
#pragma unroll
        for (int i = 0; i < 3; ++i)
#pragma unroll
            for (int r = 0; r < 4; ++r) accO[i][r] *= alpha[r];

        // P (C-layout) -> LDS (row-major) -> A-fragments
#pragma unroll
        for (int ct = 0; ct < 4; ++ct)
#pragma unroll
            for (int r = 0; r < 4; ++r)
                Plds[w][lg * 4 + r][ct * 16 + lr] = f2bf(p[ct][r]);

        // O += P V   (per-wave Plds region: same-wave write->read, compiler inserts waitcnt)
#pragma unroll
        for (int kb = 0; kb < 2; ++kb) {
            short8 ap = *reinterpret_cast<const short8*>(&Plds[w][lr][kb * 32 + lg * 8]);
#pragma unroll
            for (int et = 0; et < 3; ++et) {
                short8 bv = *reinterpret_cast<const short8*>(&Vlds[et * 16 + lr][kb * 32 + lg * 8]);
                accO[et] = __builtin_amdgcn_mfma_f32_16x16x32_bf16(ap, bv, accO[et], 0, 0, 0);
            }
        }
        __syncthreads();
    }

    // normalize and write wv in [bp][n][h*48+e] layout (k-contiguous for out-proj)
#pragma unroll
    for (int et = 0; et < 3; ++et)
#pragma unroll
        for (int r = 0; r < 4; ++r) {
            int nn = rt * 64 + w * 16 + lg * 4 + r;
            int he = h * PDIM + et * 16 + lr;
            wv_ws[((size_t)bp * NN + nn) * DD + he] = f2bf(accO[et][r] / lrun[r]);
        }
}

// ---------------- output projection GEMM ----------------
// grid (16 row-tiles, 32 bp), block 256; wave: 16 rows x 384 cols
__global__ __launch_bounds__(256) void oproj_kernel(
    const u16* __restrict__ wv_ws, const u16* __restrict__ Wot,
    const float* __restrict__ b_o, float* __restrict__ out) {
    int rt = blockIdx.x, bp = blockIdx.y;
    int tid = threadIdx.x;
    int w = tid >> 6, l = tid & 63;
    int lr = l & 15, lg = l >> 4;
    int n = rt * 64 + w * 16 + lr;
    const u16* arow = wv_ws + ((size_t)bp * NN + n) * DD;

    f32x4 acc[24];
#pragma unroll
    for (int i = 0; i < 24; ++i) acc[i] = (f32x4)(0.f);

#pragma unroll 1
    for (int ks = 0; ks < 12; ++ks) {
        int k0 = ks * 32 + lg * 8;
        short8 af = *reinterpret_cast<const short8*>(arow + k0);
#pragma unroll
        for (int ct = 0; ct < 24; ++ct) {
            short8 bf = *reinterpret_cast<const short8*>(Wot + (size_t)(ct * 16 + lr) * DD + k0);
            acc[ct] = __builtin_amdgcn_mfma_f32_16x16x32_bf16(af, bf, acc[ct], 0, 0, 0);
        }
    }

#pragma unroll
    for (int ct = 0; ct < 24; ++ct) {
        int d = ct * 16 + lr;
        float bo = b_o[d];
#pragma unroll
        for (int r = 0; r < 4; ++r) {
            int nn = rt * 64 + w * 16 + lg * 4 + r;
            out[((size_t)bp * NN + nn) * DD + d] = acc[ct][r] + bo;
        }
    }
}

extern "C" void kernel_launch(void* const* d_in, const int* in_sizes, int n_in,
                              void* d_out, int out_size, void* d_ws, size_t ws_size,
                              hipStream_t stream) {
    const float* x     = (const float*)d_in[0];
    const float* w_qkv = (const float*)d_in[1];
    const float* b_qkv = (const float*)d_in[2];
    const float* w_o   = (const float*)d_in[3];
    const float* b_o   = (const float*)d_in[4];
    float* out = (float*)d_out;

    char* ws = (char*)d_ws;
    size_t off = 0;
    u16* Wt    = (u16*)(ws + off); off += (size_t)OO * DD * 2;          // 884,736
    u16* Wot   = (u16*)(ws + off); off += (size_t)DD * DD * 2;          // 294,912
    u16* q_ws  = (u16*)(ws + off); off += (size_t)BP * HH * NN * EP * 2; // 33.5 MB
    u16* k_ws  = (u16*)(ws + off); off += (size_t)BP * HH * NN * EP * 2; // 33.5 MB
    u16* vt_ws = (u16*)(ws + off); off += (size_t)BP * HH * PDIM * NN * 2; // 25.2 MB
    u16* wv_ws = (u16*)(ws + off); off += (size_t)BP * NN * DD * 2;     // 25.2 MB
    (void)ws_size;

    prep_kernel<<<1152, 256, 0, stream>>>(w_qkv, w_o, Wt, Wot);
    qkv_kernel<<<dim3(16, 32, 4), 256, 0, stream>>>(x, b_qkv, Wt, q_ws, k_ws, vt_ws);
    attn_kernel<<<dim3(16, 256), 256, 0, stream>>>(q_ws, k_ws, vt_ws, wv_ws);
    oproj_kernel<<<dim3(16, 32), 256, 0, stream>>>(wv_ws, Wot, b_o, out);
}

// Round 6
// 408.091 us; speedup vs baseline: 1.5266x; 1.5266x over previous
//
#include <hip/hip_runtime.h>
#include <hip/hip_bf16.h>

// MultiHeadSelfAttentionEinSum2D: B=8,P=4,N=1024,D=384,H=8,PD=48
// prep (weights->bf16 transposed, x->bf16) -> QKV tiled GEMM (MFMA, LDS-staged)
// -> flash attention (MFMA) -> output projection tiled GEMM -> fp32 out

#define BP 32
#define NN 1024
#define DD 384
#define HH 8
#define PDIM 48
#define E3 144
#define OO 1152
#define EP 64
#define MTOT (BP * NN)  // 32768

typedef unsigned short u16;
typedef __attribute__((ext_vector_type(8))) short short8;
typedef __attribute__((ext_vector_type(4))) float f32x4;

__device__ __forceinline__ u16 f2bf(float f) {
    union { float f; unsigned int u; } v;
    v.f = f;
    unsigned int u = v.u;
    unsigned int r = u + 0x7FFFu + ((u >> 16) & 1u);  // RNE
    return (u16)(r >> 16);
}

// async global->LDS, 16B per lane. LDS dest: wave-uniform base + lane*16 (linear).
__device__ __forceinline__ void gload16(const u16* g, u16* l) {
    __builtin_amdgcn_global_load_lds(
        (const __attribute__((address_space(1))) void*)g,
        (__attribute__((address_space(3))) void*)l, 16, 0, 0);
}

// ---------------- prep: weights -> bf16 (k-contiguous), x -> bf16 ----------------
// Wt[o][d]   = w_qkv[d][o]       (o = h*144+e3; 1152 x 384)
// Wot[d][he] = w_o[e][h][d]      (row = out-dim d, col = he = h*48+e; 384 x 384)
// xb[m][d]   = bf16(x[m][d])     (32768 x 384)
__global__ void prep_kernel(const float* __restrict__ x,
                            const float* __restrict__ w_qkv,
                            const float* __restrict__ w_o,
                            u16* __restrict__ Wt, u16* __restrict__ Wot,
                            u16* __restrict__ xb) {
    int stride = gridDim.x * blockDim.x;
    int t0 = blockIdx.x * blockDim.x + threadIdx.x;
    for (int i = t0; i < OO * DD; i += stride) {
        int o = i / DD, d = i - o * DD;
        Wt[i] = f2bf(w_qkv[(size_t)d * OO + o]);
    }
    for (int i = t0; i < DD * DD; i += stride) {
        int dd = i / DD, he = i - dd * DD;
        int h = he / PDIM, e = he - h * PDIM;
        Wot[i] = f2bf(w_o[((size_t)e * HH + h) * DD + dd]);
    }
    for (int i = t0; i < MTOT * DD / 8; i += stride) {
        const float4* xp = reinterpret_cast<const float4*>(x + (size_t)i * 8);
        float4 a0 = xp[0], a1 = xp[1];
        short8 v;
        v[0] = (short)f2bf(a0.x); v[1] = (short)f2bf(a0.y);
        v[2] = (short)f2bf(a0.z); v[3] = (short)f2bf(a0.w);
        v[4] = (short)f2bf(a1.x); v[5] = (short)f2bf(a1.y);
        v[6] = (short)f2bf(a1.z); v[7] = (short)f2bf(a1.w);
        reinterpret_cast<short8*>(xb)[i] = v;
    }
}

// ---- shared GEMM helpers: 128x64 bf16 tile, XOR-swizzled (p = g ^ (row&7)) ----
// Stage: LDS linear dest (gload_lds constraint), global source pre-inverse-swizzled.
__device__ __forceinline__ void stage_tile(const u16* __restrict__ src, int ld,
                                           u16* lds, int tid) {
#pragma unroll
    for (int i = 0; i < 4; ++i) {
        int idx = i * 256 + tid;          // 16B chunk index, 0..1023
        int row = idx >> 3, p = idx & 7;  // 8 chunks per 128B row
        int g = p ^ (row & 7);
        gload16(src + (size_t)row * ld + g * 8, lds + idx * 8);
    }
}
// Read fragment: want global k-chunk (kk*4+lg); physical chunk = same XOR.
// Lanes lr=0..15 hit 8 distinct chunk slots across rows -> conflict-free (2-way).
__device__ __forceinline__ short8 lds_frag(const u16* lds, int row, int kk, int lg) {
    int p = (kk * 4 + lg) ^ (row & 7);
    return *reinterpret_cast<const short8*>(lds + row * 64 + p * 8);
}

// ---------------- QKV projection: C[32768x1152] = xb * Wt^T ----------------
// grid (256 m-tiles, 9 n-tiles), 4 waves, 128x128 tile, BK=64 (6 K-steps).
__global__ __launch_bounds__(256) void qkv_kernel(
    const u16* __restrict__ xb, const float* __restrict__ b_qkv,
    const u16* __restrict__ Wt,
    u16* __restrict__ q_ws, u16* __restrict__ k_ws, u16* __restrict__ vt_ws) {
    __shared__ alignas(16) u16 Al[128 * 64];
    __shared__ alignas(16) u16 Bl[128 * 64];
    int mt = blockIdx.x, nt = blockIdx.y;
    int tid = threadIdx.x;
    int w = tid >> 6, l = tid & 63, lr = l & 15, lg = l >> 4;
    int wr = w >> 1, wc = w & 1;  // 2x2 wave grid, 64x64 per wave

    const u16* Abase = xb + (size_t)mt * 128 * DD;
    const u16* Bbase = Wt + (size_t)nt * 128 * DD;

    f32x4 acc[4][4];
#pragma unroll
    for (int mi = 0; mi < 4; ++mi)
#pragma unroll
        for (int ni = 0; ni < 4; ++ni) acc[mi][ni] = (f32x4)(0.f);

#pragma unroll 1
    for (int kt = 0; kt < 6; ++kt) {
        __syncthreads();  // all waves done reading previous tile
        stage_tile(Abase + kt * 64, DD, Al, tid);
        stage_tile(Bbase + kt * 64, DD, Bl, tid);
        __syncthreads();  // compiler drains vmcnt(0) before s_barrier -> tile ready
#pragma unroll
        for (int kk = 0; kk < 2; ++kk) {
            short8 a[4], b[4];
#pragma unroll
            for (int mi = 0; mi < 4; ++mi) a[mi] = lds_frag(Al, wr * 64 + mi * 16 + lr, kk, lg);
#pragma unroll
            for (int ni = 0; ni < 4; ++ni) b[ni] = lds_frag(Bl, wc * 64 + ni * 16 + lr, kk, lg);
#pragma unroll
            for (int mi = 0; mi < 4; ++mi)
#pragma unroll
                for (int ni = 0; ni < 4; ++ni)
                    acc[mi][ni] = __builtin_amdgcn_mfma_f32_16x16x32_bf16(a[mi], b[ni], acc[mi][ni], 0, 0, 0);
        }
    }

    // epilogue: scatter into q/k (padded [n][64], pad zeroed) and v^T ([e][n])
#pragma unroll
    for (int ni = 0; ni < 4; ++ni) {
        int o = nt * 128 + wc * 64 + ni * 16 + lr;
        int h = o / E3, e3 = o - h * E3;
        float bias = b_qkv[o];
#pragma unroll
        for (int mi = 0; mi < 4; ++mi)
#pragma unroll
            for (int r = 0; r < 4; ++r) {
                int M = mt * 128 + wr * 64 + mi * 16 + lg * 4 + r;
                int bp = M >> 10, nn = M & 1023;
                size_t bh = (size_t)bp * HH + h;
                u16 bv = f2bf(acc[mi][ni][r] + bias);
                if (e3 < 48) {
                    size_t base = (bh * NN + nn) * EP;
                    q_ws[base + e3] = bv;
                    if (e3 < 16) q_ws[base + 48 + e3] = 0;
                } else if (e3 < 96) {
                    int c = e3 - 48;
                    size_t base = (bh * NN + nn) * EP;
                    k_ws[base + c] = bv;
                    if (c < 16) k_ws[base + 48 + c] = 0;
                } else {
                    vt_ws[(bh * PDIM + (e3 - 96)) * NN + nn] = bv;
                }
            }
    }
}

// ---------------- flash attention (unchanged) ----------------
__global__ __launch_bounds__(256) void attn_kernel(
    const u16* __restrict__ q_ws, const u16* __restrict__ k_ws,
    const u16* __restrict__ vt_ws, u16* __restrict__ wv_ws) {
    int rt = blockIdx.x;    // 0..15
    int bph = blockIdx.y;   // 0..255
    int bp = bph >> 3, h = bph & 7;
    int tid = threadIdx.x;
    int w = tid >> 6, l = tid & 63;
    int lr = l & 15, lg = l >> 4;

    __shared__ alignas(16) u16 Klds[64][72];
    __shared__ alignas(16) u16 Vlds[48][72];
    __shared__ alignas(16) u16 Plds[4][16][72];

    int qn = rt * 64 + w * 16 + lr;
    const u16* qrow = q_ws + ((size_t)bph * NN + qn) * EP;
    short8 aq0 = *reinterpret_cast<const short8*>(qrow + lg * 8);
    short8 aq1 = *reinterpret_cast<const short8*>(qrow + 32 + lg * 8);

    f32x4 accO[3];
#pragma unroll
    for (int i = 0; i < 3; ++i) accO[i] = (f32x4)(0.f);
    float mrun[4], lrun[4];
#pragma unroll
    for (int r = 0; r < 4; ++r) { mrun[r] = -1e30f; lrun[r] = 0.f; }
    const float inv_scale = 0.14433756729740643f;  // 1/sqrt(48)

#pragma unroll 1
    for (int jc = 0; jc < 16; ++jc) {
        {
            int j = tid >> 2, seg = (tid & 3) * 16;
            const u16* src = k_ws + ((size_t)bph * NN + jc * 64 + j) * EP + seg;
            *reinterpret_cast<short8*>(&Klds[j][seg]) = *reinterpret_cast<const short8*>(src);
            *reinterpret_cast<short8*>(&Klds[j][seg + 8]) = *reinterpret_cast<const short8*>(src + 8);
            if (tid < 192) {
                int e = tid >> 2;
                const u16* vsrc = vt_ws + ((size_t)bph * PDIM + e) * NN + jc * 64 + seg;
                *reinterpret_cast<short8*>(&Vlds[e][seg]) = *reinterpret_cast<const short8*>(vsrc);
                *reinterpret_cast<short8*>(&Vlds[e][seg + 8]) = *reinterpret_cast<const short8*>(vsrc + 8);
            }
        }
        __syncthreads();

        f32x4 s[4];
#pragma unroll
        for (int ct = 0; ct < 4; ++ct) {
            s[ct] = (f32x4)(0.f);
            short8 bk0 = *reinterpret_cast<const short8*>(&Klds[ct * 16 + lr][lg * 8]);
            short8 bk1 = *reinterpret_cast<const short8*>(&Klds[ct * 16 + lr][32 + lg * 8]);
            s[ct] = __builtin_amdgcn_mfma_f32_16x16x32_bf16(aq0, bk0, s[ct], 0, 0, 0);
            s[ct] = __builtin_amdgcn_mfma_f32_16x16x32_bf16(aq1, bk1, s[ct], 0, 0, 0);
        }
#pragma unroll
        for (int ct = 0; ct < 4; ++ct) s[ct] *= inv_scale;

        float mnew[4], alpha[4];
#pragma unroll
        for (int r = 0; r < 4; ++r) {
            float m = fmaxf(fmaxf(s[0][r], s[1][r]), fmaxf(s[2][r], s[3][r]));
#pragma unroll
            for (int off = 1; off < 16; off <<= 1) m = fmaxf(m, __shfl_xor(m, off));
            mnew[r] = fmaxf(mrun[r], m);
            alpha[r] = __expf(mrun[r] - mnew[r]);
            mrun[r] = mnew[r];
        }
        float p[4][4];
#pragma unroll
        for (int ct = 0; ct < 4; ++ct)
#pragma unroll
            for (int r = 0; r < 4; ++r) p[ct][r] = __expf(s[ct][r] - mnew[r]);
#pragma unroll
        for (int r = 0; r < 4; ++r) {
            float rs = p[0][r] + p[1][r] + p[2][r] + p[3][r];
#pragma unroll
            for (int off = 1; off < 16; off <<= 1) rs += __shfl_xor(rs, off);
            lrun[r] = lrun[r] * alpha[r] + rs;
        }
#pragma unroll
        for (int i = 0; i < 3; ++i)
#pragma unroll
            for (int r = 0; r < 4; ++r) accO[i][r] *= alpha[r];

#pragma unroll
        for (int ct = 0; ct < 4; ++ct)
#pragma unroll
            for (int r = 0; r < 4; ++r)
                Plds[w][lg * 4 + r][ct * 16 + lr] = f2bf(p[ct][r]);

#pragma unroll
        for (int kb = 0; kb < 2; ++kb) {
            short8 ap = *reinterpret_cast<const short8*>(&Plds[w][lr][kb * 32 + lg * 8]);
#pragma unroll
            for (int et = 0; et < 3; ++et) {
                short8 bv = *reinterpret_cast<const short8*>(&Vlds[et * 16 + lr][kb * 32 + lg * 8]);
                accO[et] = __builtin_amdgcn_mfma_f32_16x16x32_bf16(ap, bv, accO[et], 0, 0, 0);
            }
        }
        __syncthreads();
    }

#pragma unroll
    for (int et = 0; et < 3; ++et)
#pragma unroll
        for (int r = 0; r < 4; ++r) {
            int nn = rt * 64 + w * 16 + lg * 4 + r;
            int he = h * PDIM + et * 16 + lr;
            wv_ws[((size_t)bp * NN + nn) * DD + he] = f2bf(accO[et][r] / lrun[r]);
        }
}

// ---------------- output projection: out[32768x384] = wv * Wot^T + b_o ----------------
__global__ __launch_bounds__(256) void oproj_kernel(
    const u16* __restrict__ wv_ws, const u16* __restrict__ Wot,
    const float* __restrict__ b_o, float* __restrict__ out) {
    __shared__ alignas(16) u16 Al[128 * 64];
    __shared__ alignas(16) u16 Bl[128 * 64];
    int mt = blockIdx.x, nt = blockIdx.y;  // 256 x 3
    int tid = threadIdx.x;
    int w = tid >> 6, l = tid & 63, lr = l & 15, lg = l >> 4;
    int wr = w >> 1, wc = w & 1;

    const u16* Abase = wv_ws + (size_t)mt * 128 * DD;
    const u16* Bbase = Wot + (size_t)nt * 128 * DD;

    f32x4 acc[4][4];
#pragma unroll
    for (int mi = 0; mi < 4; ++mi)
#pragma unroll
        for (int ni = 0; ni < 4; ++ni) acc[mi][ni] = (f32x4)(0.f);

#pragma unroll 1
    for (int kt = 0; kt < 6; ++kt) {
        __syncthreads();
        stage_tile(Abase + kt * 64, DD, Al, tid);
        stage_tile(Bbase + kt * 64, DD, Bl, tid);
        __syncthreads();
#pragma unroll
        for (int kk = 0; kk < 2; ++kk) {
            short8 a[4], b[4];
#pragma unroll
            for (int mi = 0; mi < 4; ++mi) a[mi] = lds_frag(Al, wr * 64 + mi * 16 + lr, kk, lg);
#pragma unroll
            for (int ni = 0; ni < 4; ++ni) b[ni] = lds_frag(Bl, wc * 64 + ni * 16 + lr, kk, lg);
#pragma unroll
            for (int mi = 0; mi < 4; ++mi)
#pragma unroll
                for (int ni = 0; ni < 4; ++ni)
                    acc[mi][ni] = __builtin_amdgcn_mfma_f32_16x16x32_bf16(a[mi], b[ni], acc[mi][ni], 0, 0, 0);
        }
    }

#pragma unroll
    for (int ni = 0; ni < 4; ++ni) {
        int d = nt * 128 + wc * 64 + ni * 16 + lr;
        float bo = b_o[d];
#pragma unroll
        for (int mi = 0; mi < 4; ++mi)
#pragma unroll
            for (int r = 0; r < 4; ++r) {
                int M = mt * 128 + wr * 64 + mi * 16 + lg * 4 + r;
                out[(size_t)M * DD + d] = acc[mi][ni][r] + bo;
            }
    }
}

extern "C" void kernel_launch(void* const* d_in, const int* in_sizes, int n_in,
                              void* d_out, int out_size, void* d_ws, size_t ws_size,
                              hipStream_t stream) {
    const float* x     = (const float*)d_in[0];
    const float* w_qkv = (const float*)d_in[1];
    const float* b_qkv = (const float*)d_in[2];
    const float* w_o   = (const float*)d_in[3];
    const float* b_o   = (const float*)d_in[4];
    float* out = (float*)d_out;

    char* ws = (char*)d_ws;
    size_t off = 0;
    u16* Wt    = (u16*)(ws + off); off += (size_t)OO * DD * 2;            // 0.88 MB
    u16* Wot   = (u16*)(ws + off); off += (size_t)DD * DD * 2;            // 0.29 MB
    u16* q_ws  = (u16*)(ws + off); off += (size_t)BP * HH * NN * EP * 2;  // 33.5 MB
    u16* k_ws  = (u16*)(ws + off); off += (size_t)BP * HH * NN * EP * 2;  // 33.5 MB
    u16* vt_ws = (u16*)(ws + off); off += (size_t)BP * HH * PDIM * NN * 2; // 25.2 MB
    u16* wv_ws = (u16*)(ws + off); off += (size_t)BP * NN * DD * 2;       // 25.2 MB
    u16* xb    = wv_ws;  // alias: xb dead before attn writes wv_ws
    (void)ws_size;

    prep_kernel<<<2048, 256, 0, stream>>>(x, w_qkv, w_o, Wt, Wot, xb);
    qkv_kernel<<<dim3(256, 9), 256, 0, stream>>>(xb, b_qkv, Wt, q_ws, k_ws, vt_ws);
    attn_kernel<<<dim3(16, 256), 256, 0, stream>>>(q_ws, k_ws, vt_ws, wv_ws);
    oproj_kernel<<<dim3(256, 3), 256, 0, stream>>>(wv_ws, Wot, b_o, out);
}